// Round 5
// baseline (182.176 us; speedup 1.0000x reference)
//
#include <hip/hip_runtime.h>

// Disable FMA contraction so float rounding matches the numpy reference
// op-for-op (threshold compares at 0.5 and argmax ties depend on it).
#pragma clang fp contract(off)

#define BB 32     // batch
#define NN 100    // gt boxes per image
#define PP 8732   // priors
#define CH 16     // j-chunk for the transposed row-max reduce
#define LDW 257   // padded row stride (u32) -> 2-way banks only (free)
#define NBX 35    // blocks along the prior axis

// -------------------------------------------------------------------------
// Single fused kernel. Thread owns prior p of batch b for BOTH phases, so
// the prior box and the column-argmax (best_ov/best_j) stay in registers.
//
// Phase 1 (IoU): GT boxes via wave-uniform scalar loads; column max/argmax
//   over gts (strict > = first occurrence); row max over priors via the
//   chunked LDS transpose into persistent s_part[j][seg] u64 keys
//   ((iou_bits<<32)|~p : max == max-iou then min-p); one deferred batch of
//   100 device atomicMax per block.
// Barrier: __threadfence + per-b arrival counter; t0 spins until all 35
//   blocks of batch b arrived. Safe: LDS 30.2KB -> 5 blocks/CU -> 1280
//   resident slots >= 1120 blocks, all co-resident; all comms are
//   device-scope atomics (coherent across XCDs).
// Phase 2 (encode): coherent gkey re-read (RMW), LDS scatter of forced
//   matches (max j = last-write-wins, matching the reference scatter),
//   then encode straight from registers.
// -------------------------------------------------------------------------
__global__ __launch_bounds__(256, 5) void k_fused(
    const float* __restrict__ gt,        // [B,N,4] xyxy
    const int*   __restrict__ labels,    // [B,N]
    const float* __restrict__ priors,    // [P,4] cxcywh
    unsigned long long* __restrict__ gkey,  // [B,N], pre-zeroed
    unsigned int* __restrict__ done,        // [B], pre-zeroed
    float* __restrict__ loc_out,         // [B,P,4]
    float* __restrict__ conf_out)        // [B,P]
{
    __shared__ unsigned int s_iou[CH * LDW];          // 16.4 KB
    __shared__ unsigned long long s_part[NN][17];     // 13.6 KB
    int* s_forced = (int*)s_iou;                      // aliased after phase 1

    const int b = blockIdx.y;
    const int t = threadIdx.x;
    const int p = blockIdx.x * 256 + t;
    const bool valid = p < PP;
    const int pc = valid ? p : (PP - 1);

    const float4 pr = reinterpret_cast<const float4*>(priors)[pc];
    const float px1 = pr.x - pr.z * 0.5f;
    const float py1 = pr.y - pr.w * 0.5f;
    const float px2 = pr.x + pr.z * 0.5f;
    const float py2 = pr.y + pr.w * 0.5f;
    const float area_b = (px2 - px1) * (py2 - py1);

    // wave-uniform base: compiler scalarizes these loads (s_load_dwordx4)
    const float4* __restrict__ gtb =
        reinterpret_cast<const float4*>(gt) + b * NN;

    float best_ov = -1.0f;
    int best_j = 0;

    for (int jc = 0; jc < NN; jc += CH) {
        const int nr = (NN - jc) < CH ? (NN - jc) : CH;

        #pragma unroll 4
        for (int jj = 0; jj < nr; ++jj) {
            float4 g = gtb[jc + jj];                 // uniform -> SGPRs
            float area_a = (g.z - g.x) * (g.w - g.y);
            float ltx = fmaxf(g.x, px1), lty = fmaxf(g.y, py1);
            float rbx = fminf(g.z, px2), rby = fminf(g.w, py2);
            float w = fmaxf(rbx - ltx, 0.0f), h = fmaxf(rby - lty, 0.0f);
            float inter = w * h;
            float iou = inter / (area_a + area_b - inter + 1e-6f);
            if (!valid) iou = 0.0f;       // ties lose to valid via min-p scan
            if (iou > best_ov) { best_ov = iou; best_j = jc + jj; }
            s_iou[jj * LDW + t] = __float_as_uint(iou);  // iou>=0: uint order
        }
        __syncthreads();

        // phase A: 16 threads per row, each scans 16 ascending-p columns
        {
            const int r = t & 15;
            const int s = t >> 4;
            if (r < nr) {
                const unsigned int* row = s_iou + r * LDW + s * 16;
                unsigned int bb = row[0];
                int bi = 0;
                #pragma unroll
                for (int i = 1; i < 16; ++i) {
                    unsigned int v = row[i];
                    if (v > bb) { bb = v; bi = i; }   // strict > = min p
                }
                int pw = blockIdx.x * 256 + s * 16 + bi;
                s_part[jc + r][s] = ((unsigned long long)bb << 32) |
                                    (unsigned int)(~pw);
            }
        }
        __syncthreads();   // s_iou reusable next chunk
    }

    // deferred phase B: one merge + one device atomic per gt
    if (t < NN) {
        unsigned long long best = s_part[t][0];
        #pragma unroll
        for (int s = 1; s < 16; ++s) {
            unsigned long long k = s_part[t][s];
            if (k > best) best = k;                   // ~p breaks iou ties
        }
        atomicMax(&gkey[b * NN + t], best);
    }
    __threadfence();       // make this thread's atomic globally visible
    __syncthreads();

    // grid barrier over the 35 blocks of batch b (all blocks co-resident)
    if (t == 0) {
        if (atomicAdd(&done[b], 1u) + 1u < (unsigned)NBX) {
            while (atomicAdd(&done[b], 0u) < (unsigned)NBX)
                __builtin_amdgcn_s_sleep(2);
        }
    }
    __syncthreads();

    // forced-match scatter (max j = last-write-wins, as the reference)
    s_forced[t] = -1;
    __syncthreads();
    if (t < NN) {
        unsigned long long k = atomicAdd(&gkey[b * NN + t], 0ull);  // coherent
        int kp = (int)~(unsigned int)(k & 0xFFFFFFFFull);
        int lp = kp - blockIdx.x * 256;
        if ((unsigned)lp < 256u) atomicMax(&s_forced[lp], t);
    }
    __syncthreads();

    if (!valid) return;
    const int forced_j = s_forced[t];
    const int j    = (forced_j >= 0) ? forced_j : best_j;
    const int lab  = labels[b * NN + j];
    const int conf = (forced_j < 0 && best_ov < 0.5f) ? 0 : (lab + 1);

    const float4 g = reinterpret_cast<const float4*>(gt)[b * NN + j];
    const float mcx = (g.x + g.z) * 0.5f;
    const float mcy = (g.y + g.w) * 0.5f;
    const float mw  = fmaxf(g.z - g.x, 1e-6f);
    const float mh  = fmaxf(g.w - g.y, 1e-6f);
    const float gcx = (mcx - pr.x) / (0.1f * pr.z);
    const float gcy = (mcy - pr.y) / (0.1f * pr.w);
    const float gw  = logf(mw / pr.z) / 0.2f;
    const float gh  = logf(mh / pr.w) / 0.2f;

    reinterpret_cast<float4*>(loc_out)[b * PP + p] =
        make_float4(gcx, gcy, gw, gh);
    conf_out[b * PP + p] = (float)conf;
}

extern "C" void kernel_launch(void* const* d_in, const int* in_sizes, int n_in,
                              void* d_out, int out_size, void* d_ws, size_t ws_size,
                              hipStream_t stream) {
    const float* gt     = (const float*)d_in[0];  // [32,100,4] f32
    const int*   labels = (const int*)  d_in[1];  // [32,100] i32
    const float* priors = (const float*)d_in[2];  // [8732,4] f32

    float* loc  = (float*)d_out;                         // [32,8732,4]
    float* conf = (float*)d_out + (size_t)BB * PP * 4;   // [32,8732]

    unsigned long long* gkey = (unsigned long long*)d_ws;          // [32,100]
    unsigned int* done = (unsigned int*)((char*)d_ws + (size_t)BB * NN * 8);  // [32]

    // keys + arrival counters must start at 0 (ws is poisoned 0xAA each call)
    hipMemsetAsync(d_ws, 0, (size_t)BB * NN * 8 + BB * 4, stream);

    dim3 grid(NBX, BB);
    k_fused<<<grid, 256, 0, stream>>>(gt, labels, priors, gkey, done,
                                      loc, conf);
}

// Round 6
// 96.603 us; speedup vs baseline: 1.8858x; 1.8858x over previous
//
#include <hip/hip_runtime.h>

// Disable FMA contraction so float rounding matches the numpy reference
// op-for-op (threshold compares at 0.5 and argmax ties depend on it).
#pragma clang fp contract(off)

#define BB 32     // batch
#define NN 100    // gt boxes per image
#define PP 8732   // priors
#define CH 16     // j-chunk for the transposed row-max reduce
#define LDW 257   // padded row stride (u32) -> 2-way banks only (free)
#define NBX 35    // blocks along the prior axis

// -------------------------------------------------------------------------
// Kernel 1: thread owns prior p of batch b.
//  - GT corners via wave-uniform scalar loads; area_a via LDS prologue
//    (avoids the 1-SGPR-per-VALU v_mov tax, ~5 VALU/j -> 1 ds_read/j).
//  - Out-of-range lanes compute the real IoU of prior PP-1 (no per-j
//    clamp): duplicate columns tie with p=8731's value and lose the
//    (iou<<32)|~p min-p tie-break, so they can never win a row.
//  - column max/argmax over gts (strict > = first occurrence) -> m8 byte
//  - row max over priors: chunked LDS transpose -> persistent
//    s_part[j][seg] u64 keys; phase B merges 16 segs and PLAIN-STORES the
//    per-block key to part[b][bx][j] (USE_PART) - no atomics, no memset -
//    or atomicMax into gkey[b][j] (fallback when ws is small).
// -------------------------------------------------------------------------
template <bool USE_PART>
__global__ __launch_bounds__(256) void k_iou_pass(
    const float* __restrict__ gt,        // [B,N,4] xyxy
    const float* __restrict__ priors,    // [P,4] cxcywh
    unsigned long long* __restrict__ red,   // part [B][NBX][NN] or gkey [B][N]
    unsigned char* __restrict__ m8)         // [B,P]: best_j | (bg?0x80:0)
{
    __shared__ unsigned int s_iou[CH * LDW];          // 16.4 KB
    __shared__ unsigned long long s_part[NN][17];     // 13.6 KB
    __shared__ float s_area[NN];                      // 400 B

    const int b = blockIdx.y;
    const int t = threadIdx.x;
    const int p = blockIdx.x * 256 + t;
    const bool valid = p < PP;
    const int pc = valid ? p : (PP - 1);

    // wave-uniform base: compiler scalarizes these loads (s_load_dwordx4)
    const float4* __restrict__ gtb =
        reinterpret_cast<const float4*>(gt) + b * NN;

    if (t < NN) {
        float4 g = gtb[t];                // per-thread gather here (vector)
        s_area[t] = (g.z - g.x) * (g.w - g.y);
    }

    const float4 pr = reinterpret_cast<const float4*>(priors)[pc];
    const float px1 = pr.x - pr.z * 0.5f;
    const float py1 = pr.y - pr.w * 0.5f;
    const float px2 = pr.x + pr.z * 0.5f;
    const float py2 = pr.y + pr.w * 0.5f;
    const float area_b = (px2 - px1) * (py2 - py1);

    float best_ov = -1.0f;
    int best_j = 0;

    __syncthreads();   // s_area ready

    for (int jc = 0; jc < NN; jc += CH) {
        const int nr = (NN - jc) < CH ? (NN - jc) : CH;

        #pragma unroll
        for (int jj = 0; jj < CH; ++jj) {
            if (jj >= nr) break;
            float4 g = gtb[jc + jj];                 // uniform -> SGPRs
            float area_a = s_area[jc + jj];          // broadcast ds_read
            float ltx = fmaxf(g.x, px1), lty = fmaxf(g.y, py1);
            float rbx = fminf(g.z, px2), rby = fminf(g.w, py2);
            float w = fmaxf(rbx - ltx, 0.0f), h = fmaxf(rby - lty, 0.0f);
            float inter = w * h;
            float iou = inter / (area_a + area_b - inter + 1e-6f);
            if (iou > best_ov) { best_ov = iou; best_j = jc + jj; }
            s_iou[jj * LDW + t] = __float_as_uint(iou);  // iou>=0: uint order
        }
        __syncthreads();

        // phase A: 16 threads per row, each scans 16 ascending-p columns
        {
            const int r = t & 15;
            const int s = t >> 4;
            if (r < nr) {
                const unsigned int* row = s_iou + r * LDW + s * 16;
                unsigned int bb = row[0];
                int bi = 0;
                #pragma unroll
                for (int i = 1; i < 16; ++i) {
                    unsigned int v = row[i];
                    if (v > bb) { bb = v; bi = i; }   // strict > = min p
                }
                int pw = blockIdx.x * 256 + s * 16 + bi;
                s_part[jc + r][s] = ((unsigned long long)bb << 32) |
                                    (unsigned int)(~pw);
            }
        }
        __syncthreads();   // s_iou reusable next chunk; s_part visible
    }

    // phase B: merge 16 segment partials per gt; plain store (or atomic)
    if (t < NN) {
        unsigned long long best = s_part[t][0];
        #pragma unroll
        for (int s = 1; s < 16; ++s) {
            unsigned long long k = s_part[t][s];
            if (k > best) best = k;                   // ~p breaks iou ties
        }
        if (USE_PART) {
            red[((size_t)b * NBX + blockIdx.x) * NN + t] = best;
        } else {
            atomicMax(&red[b * NN + t], best);
        }
    }
    if (valid) {
        m8[b * PP + p] =
            (unsigned char)(best_j | ((best_ov < 0.5f) ? 0x80 : 0));
    }
}

// -------------------------------------------------------------------------
// Kernel 2: reduce the 35 per-block row keys (USE_PART) or read gkey,
// scatter forced matches into LDS (max j = last-write-wins, matching the
// reference scatter), then encode.
// -------------------------------------------------------------------------
template <bool USE_PART>
__global__ __launch_bounds__(256) void k_encode(
    const float* __restrict__ gt,        // [B,N,4]
    const int*   __restrict__ labels,    // [B,N]
    const float* __restrict__ priors,    // [P,4]
    const unsigned long long* __restrict__ red,   // part or gkey
    const unsigned char* __restrict__ m8,         // [B,P]
    float* __restrict__ loc_out,         // [B,P,4]
    float* __restrict__ conf_out)        // [B,P]
{
    __shared__ int s_forced[256];        // local p -> forced gt j (-1 none)

    const int b = blockIdx.y;
    const int t = threadIdx.x;
    const int p = blockIdx.x * 256 + t;

    s_forced[t] = -1;
    __syncthreads();
    if (t < NN) {
        unsigned long long best;
        if (USE_PART) {
            const unsigned long long* q = red + (size_t)b * NBX * NN + t;
            best = q[0];
            #pragma unroll 5
            for (int bx = 1; bx < NBX; ++bx) {
                unsigned long long k = q[(size_t)bx * NN];
                if (k > best) best = k;
            }
        } else {
            best = red[b * NN + t];
        }
        int kp = (int)~(unsigned int)(best & 0xFFFFFFFFull);
        int lp = kp - blockIdx.x * 256;
        if ((unsigned)lp < 256u) atomicMax(&s_forced[lp], t);
    }
    __syncthreads();

    if (p >= PP) return;
    const int forced_j = s_forced[t];

    const unsigned char m = m8[b * PP + p];
    const int j    = (forced_j >= 0) ? forced_j : (m & 0x7f);
    const int lab  = labels[b * NN + j];
    const int conf = (forced_j < 0 && (m & 0x80)) ? 0 : (lab + 1);

    const float4 pr = reinterpret_cast<const float4*>(priors)[p];
    const float4 g  = reinterpret_cast<const float4*>(gt)[b * NN + j];
    const float mcx = (g.x + g.z) * 0.5f;
    const float mcy = (g.y + g.w) * 0.5f;
    const float mw  = fmaxf(g.z - g.x, 1e-6f);
    const float mh  = fmaxf(g.w - g.y, 1e-6f);
    const float gcx = (mcx - pr.x) / (0.1f * pr.z);
    const float gcy = (mcy - pr.y) / (0.1f * pr.w);
    const float gw  = logf(mw / pr.z) / 0.2f;
    const float gh  = logf(mh / pr.w) / 0.2f;

    reinterpret_cast<float4*>(loc_out)[b * PP + p] =
        make_float4(gcx, gcy, gw, gh);
    conf_out[b * PP + p] = (float)conf;
}

extern "C" void kernel_launch(void* const* d_in, const int* in_sizes, int n_in,
                              void* d_out, int out_size, void* d_ws, size_t ws_size,
                              hipStream_t stream) {
    const float* gt     = (const float*)d_in[0];  // [32,100,4] f32
    const int*   labels = (const int*)  d_in[1];  // [32,100] i32
    const float* priors = (const float*)d_in[2];  // [8732,4] f32

    float* loc  = (float*)d_out;                         // [32,8732,4]
    float* conf = (float*)d_out + (size_t)BB * PP * 4;   // [32,8732]

    const size_t part_bytes = (size_t)BB * NBX * NN * 8;   // 896,000
    const size_t m8_bytes   = (size_t)BB * PP;             // 279,424
    dim3 grid(NBX, BB);

    if (ws_size >= part_bytes + m8_bytes) {
        // atomic-free path: per-block partial keys, no memset dispatch
        unsigned long long* part = (unsigned long long*)d_ws;
        unsigned char* m8 = (unsigned char*)d_ws + part_bytes;
        k_iou_pass<true><<<grid, 256, 0, stream>>>(gt, priors, part, m8);
        k_encode<true><<<grid, 256, 0, stream>>>(gt, labels, priors, part,
                                                 m8, loc, conf);
    } else {
        // fallback: gkey + atomicMax (needs zeroed keys)
        unsigned long long* gkey = (unsigned long long*)d_ws;        // [32,100]
        unsigned char* m8 = (unsigned char*)d_ws + (size_t)BB * NN * 8;
        hipMemsetAsync(gkey, 0, (size_t)BB * NN * 8, stream);
        k_iou_pass<false><<<grid, 256, 0, stream>>>(gt, priors, gkey, m8);
        k_encode<false><<<grid, 256, 0, stream>>>(gt, labels, priors, gkey,
                                                  m8, loc, conf);
    }
}